// Round 1
// baseline (569.666 us; speedup 1.0000x reference)
//
#include <hip/hip_runtime.h>
#include <hip/hip_bf16.h>
#include <math.h>

#define N_NODES 50000
#define N_EDGES 800000
#define F 64
// padded stride for the two norm arrays in ws
#define NPAD 50048

// ---- degree histogram: one thread per edge ----
__global__ __launch_bounds__(256) void degrees_kernel(
    const int* __restrict__ src, const int* __restrict__ dst,
    float* __restrict__ deg_out, float* __restrict__ deg_in)
{
    int e = blockIdx.x * 256 + threadIdx.x;
    if (e < N_EDGES) {
        atomicAdd(&deg_out[src[e]], 1.0f);
        atomicAdd(&deg_in[dst[e]], 1.0f);
    }
}

// ---- deg -> norm, in place ----
__global__ __launch_bounds__(256) void norms_kernel(
    float* __restrict__ deg_out, float* __restrict__ deg_in)
{
    int i = blockIdx.x * 256 + threadIdx.x;
    if (i < N_NODES) {
        float a = deg_out[i];
        float b = deg_in[i];
        deg_out[i] = (a > 0.f) ? rsqrtf(a) : 0.f;
        deg_in[i]  = (b > 0.f) ? rsqrtf(b) : 0.f;
    }
}

// ---- scatter-add with source-side scaling fused (layer 1) ----
// 64 consecutive lanes handle one edge: src/dst loads are wave-uniform,
// feature reads/atomics fully coalesced.
__global__ __launch_bounds__(256) void scatter_scaled_kernel(
    const float* __restrict__ x, const float* __restrict__ norm_out,
    const int* __restrict__ src, const int* __restrict__ dst,
    float* __restrict__ agg)
{
    int gid = blockIdx.x * 256 + threadIdx.x;
    int e = gid >> 6;
    int f = gid & 63;
    if (e < N_EDGES) {
        int s = src[e];
        int d = dst[e];
        float v = x[s * F + f] * norm_out[s];
        atomicAdd(&agg[d * F + f], v);
    }
}

// ---- scatter-add, input already scaled (layer 2) ----
__global__ __launch_bounds__(256) void scatter_plain_kernel(
    const float* __restrict__ h,
    const int* __restrict__ src, const int* __restrict__ dst,
    float* __restrict__ agg)
{
    int gid = blockIdx.x * 256 + threadIdx.x;
    int e = gid >> 6;
    int f = gid & 63;
    if (e < N_EDGES) {
        int s = src[e];
        int d = dst[e];
        atomicAdd(&agg[d * F + f], h[s * F + f]);
    }
}

// ---- layer-1 GEMM: h = tanh(norm_in[n]*(agg[n]@W1) + b1) * norm_out[n] ----
// block = 256 threads = 4 rows x 64 cols; W staged in LDS (16 KB).
// Ws[k*64+f]: lanes f=0..63 consecutive -> conflict-free.
// rowS[r][k]: wave-uniform address -> broadcast.
__global__ __launch_bounds__(256) void gemm1_kernel(
    const float* __restrict__ agg, const float* __restrict__ norm_in,
    const float* __restrict__ norm_out,
    const float* __restrict__ W1, const float* __restrict__ b1,
    float* __restrict__ h_out)
{
    __shared__ float Ws[F * F];
    __shared__ float rowS[4][F];
    int tid = threadIdx.x;
    for (int i = tid; i < F * F; i += 256) Ws[i] = W1[i];
    __syncthreads();
    int r = tid >> 6;
    int f = tid & 63;
    float bias = b1[f];
    for (int base = blockIdx.x * 4; base < N_NODES; base += gridDim.x * 4) {
        int n = base + r;
        if (n < N_NODES) rowS[r][f] = agg[n * F + f];
        __syncthreads();
        if (n < N_NODES) {
            float acc = 0.f;
            #pragma unroll
            for (int k = 0; k < F; ++k) acc += rowS[r][k] * Ws[k * F + f];
            float z = acc * norm_in[n] + bias;
            h_out[n * F + f] = tanhf(z) * norm_out[n];
        }
        __syncthreads();
    }
}

// ---- layer-2 GEMM with J^T fold:
// z_f = norm_in[n]*(agg[n]@W2)_f + b2_f
// out[n, :32] = z[32:], out[n, 32:] = -z[:32]
// thread f writes column (f+32)&63 with sign (f<32 ? - : +)
__global__ __launch_bounds__(256) void gemm2_kernel(
    const float* __restrict__ agg, const float* __restrict__ norm_in,
    const float* __restrict__ W2, const float* __restrict__ b2,
    float* __restrict__ out)
{
    __shared__ float Ws[F * F];
    __shared__ float rowS[4][F];
    int tid = threadIdx.x;
    for (int i = tid; i < F * F; i += 256) Ws[i] = W2[i];
    __syncthreads();
    int r = tid >> 6;
    int f = tid & 63;
    float bias = b2[f];
    int oc = (f + 32) & 63;
    float sgn = (f < 32) ? -1.f : 1.f;
    for (int base = blockIdx.x * 4; base < N_NODES; base += gridDim.x * 4) {
        int n = base + r;
        if (n < N_NODES) rowS[r][f] = agg[n * F + f];
        __syncthreads();
        if (n < N_NODES) {
            float acc = 0.f;
            #pragma unroll
            for (int k = 0; k < F; ++k) acc += rowS[r][k] * Ws[k * F + f];
            float z = acc * norm_in[n] + bias;
            out[n * F + oc] = sgn * z;
        }
        __syncthreads();
    }
}

extern "C" void kernel_launch(void* const* d_in, const int* in_sizes, int n_in,
                              void* d_out, int out_size, void* d_ws, size_t ws_size,
                              hipStream_t stream) {
    const float* x  = (const float*)d_in[0];
    const int*   src = (const int*)d_in[1];
    const int*   dst = (const int*)d_in[2];
    const float* W1 = (const float*)d_in[3];
    const float* b1 = (const float*)d_in[4];
    const float* W2 = (const float*)d_in[5];
    const float* b2 = (const float*)d_in[6];
    float* out = (float*)d_out;

    float* ws = (float*)d_ws;
    float* norm_out = ws;                       // NPAD floats (deg_out -> norm_out)
    float* norm_in  = ws + NPAD;                // NPAD floats (deg_in  -> norm_in)
    float* buf_h    = ws + 2 * NPAD;            // N_NODES*F
    float* buf_agg  = buf_h + N_NODES * F;      // N_NODES*F

    // zero degree accumulators + agg buffer (ws is poisoned 0xAA each call)
    hipMemsetAsync(norm_out, 0, 2 * NPAD * sizeof(float), stream);
    hipMemsetAsync(buf_agg, 0, (size_t)N_NODES * F * sizeof(float), stream);

    degrees_kernel<<<(N_EDGES + 255) / 256, 256, 0, stream>>>(src, dst, norm_out, norm_in);
    norms_kernel<<<(N_NODES + 255) / 256, 256, 0, stream>>>(norm_out, norm_in);

    // layer 1
    scatter_scaled_kernel<<<(N_EDGES * F) / 256, 256, 0, stream>>>(x, norm_out, src, dst, buf_agg);
    gemm1_kernel<<<1024, 256, 0, stream>>>(buf_agg, norm_in, norm_out, W1, b1, buf_h);

    // layer 2
    hipMemsetAsync(buf_agg, 0, (size_t)N_NODES * F * sizeof(float), stream);
    scatter_plain_kernel<<<(N_EDGES * F) / 256, 256, 0, stream>>>(buf_h, src, dst, buf_agg);
    gemm2_kernel<<<1024, 256, 0, stream>>>(buf_agg, norm_in, W2, b2, out);
}

// Round 2
// 407.715 us; speedup vs baseline: 1.3972x; 1.3972x over previous
//
#include <hip/hip_runtime.h>
#include <hip/hip_bf16.h>
#include <math.h>

#define N_NODES 50000
#define N_EDGES 800000
#define F 64
#define NPAD 50048   // padded per-array stride in ws (covers N_NODES+1)

// ---------------- degree histogram (int atomics) ----------------
__global__ __launch_bounds__(256) void degrees_kernel(
    const int* __restrict__ src, const int* __restrict__ dst,
    unsigned* __restrict__ deg_out_u, unsigned* __restrict__ deg_in_u)
{
    int e = blockIdx.x * 256 + threadIdx.x;
    if (e < N_EDGES) {
        atomicAdd(&deg_out_u[src[e]], 1u);
        atomicAdd(&deg_in_u[dst[e]], 1u);
    }
}

// ---------------- deg -> rsqrt norms ----------------
__global__ __launch_bounds__(256) void norms_kernel(
    const unsigned* __restrict__ deg_out_u, const unsigned* __restrict__ deg_in_u,
    float* __restrict__ norm_out, float* __restrict__ norm_in)
{
    int i = blockIdx.x * 256 + threadIdx.x;
    if (i < N_NODES) {
        unsigned a = deg_out_u[i];
        unsigned b = deg_in_u[i];
        norm_out[i] = (a > 0u) ? rsqrtf((float)a) : 0.f;
        norm_in[i]  = (b > 0u) ? rsqrtf((float)b) : 0.f;
    }
}

// ---------------- single-block exclusive scan of deg_in -> row_off ----------------
// 1024 threads, each owns a contiguous chunk of C elements.
__global__ __launch_bounds__(1024) void scan_kernel(
    const unsigned* __restrict__ deg, int* __restrict__ row_off)
{
    const int C = 49;  // 1024*49 = 50176 >= 50000
    __shared__ unsigned waveSums[16];
    int t = threadIdx.x;
    int base = t * C;
    // pass 1: local sum
    unsigned sum = 0;
    for (int i = 0; i < C; ++i) {
        int idx = base + i;
        if (idx < N_NODES) sum += deg[idx];
    }
    // wave-level inclusive scan of thread sums
    unsigned inc = sum;
    #pragma unroll
    for (int d = 1; d < 64; d <<= 1) {
        unsigned u = __shfl_up(inc, d, 64);
        if ((t & 63) >= d) inc += u;
    }
    int wid = t >> 6;
    if ((t & 63) == 63) waveSums[wid] = inc;
    __syncthreads();
    if (t == 0) {
        unsigned acc = 0;
        #pragma unroll
        for (int w = 0; w < 16; ++w) { unsigned v = waveSums[w]; waveSums[w] = acc; acc += v; }
    }
    __syncthreads();
    unsigned excl = (inc - sum) + waveSums[wid];  // exclusive prefix of this thread
    // pass 2: write exclusive offsets
    unsigned run = excl;
    for (int i = 0; i < C; ++i) {
        int idx = base + i;
        if (idx < N_NODES) { row_off[idx] = (int)run; run += deg[idx]; }
    }
    if (t == 1023) row_off[N_NODES] = (int)run;   // == N_EDGES
}

// ---------------- bucket fill: csr_src sorted by dst ----------------
__global__ __launch_bounds__(256) void csr_fill_kernel(
    const int* __restrict__ src, const int* __restrict__ dst,
    const int* __restrict__ row_off, unsigned* __restrict__ cursor,
    int* __restrict__ csr_src)
{
    int e = blockIdx.x * 256 + threadIdx.x;
    if (e < N_EDGES) {
        int d = dst[e];
        unsigned p = atomicAdd(&cursor[d], 1u);
        csr_src[row_off[d] + p] = src[e];
    }
}

// ---------------- fused layer 1: aggregate + GEMM + tanh + pre-scale ----------------
// one wave per node: lane = feature. Gathers are coalesced 256B rows; index and
// norm loads are wave-uniform (readfirstlane -> scalar path).
__global__ __launch_bounds__(256) void layer1_kernel(
    const float* __restrict__ x, const float* __restrict__ norm_out,
    const float* __restrict__ norm_in, const int* __restrict__ row_off,
    const int* __restrict__ csr_src, const float* __restrict__ W1,
    const float* __restrict__ b1, float* __restrict__ h)
{
    __shared__ float Ws[F * F];
    int tid = threadIdx.x;
    for (int i = tid; i < F * F; i += 256) Ws[i] = W1[i];
    __syncthreads();
    int wid = tid >> 6, lane = tid & 63;
    int n = blockIdx.x * 4 + wid;
    if (n >= N_NODES) return;
    int beg = __builtin_amdgcn_readfirstlane(row_off[n]);
    int end = __builtin_amdgcn_readfirstlane(row_off[n + 1]);
    float a0 = 0.f, a1 = 0.f, a2 = 0.f, a3 = 0.f;
    int i = beg;
    for (; i + 4 <= end; i += 4) {
        int s0 = __builtin_amdgcn_readfirstlane(csr_src[i]);
        int s1 = __builtin_amdgcn_readfirstlane(csr_src[i + 1]);
        int s2 = __builtin_amdgcn_readfirstlane(csr_src[i + 2]);
        int s3 = __builtin_amdgcn_readfirstlane(csr_src[i + 3]);
        float w0 = norm_out[s0], w1 = norm_out[s1], w2 = norm_out[s2], w3 = norm_out[s3];
        a0 += x[s0 * F + lane] * w0;
        a1 += x[s1 * F + lane] * w1;
        a2 += x[s2 * F + lane] * w2;
        a3 += x[s3 * F + lane] * w3;
    }
    for (; i < end; ++i) {
        int s0 = __builtin_amdgcn_readfirstlane(csr_src[i]);
        a0 += x[s0 * F + lane] * norm_out[s0];
    }
    float agg = (a0 + a1) + (a2 + a3);
    // in-wave 64x64 GEMM: acc_f = sum_k agg_k * W1[k][f]
    float acc = 0.f;
    #pragma unroll
    for (int k = 0; k < F; ++k) {
        float ak = __shfl(agg, k, 64);
        acc += ak * Ws[k * F + lane];
    }
    float z = tanhf(acc * norm_in[n] + b1[lane]);
    h[n * F + lane] = z * norm_out[n];   // pre-scale for layer-2 source side
}

// ---------------- fused layer 2: aggregate + GEMM + J^T fold ----------------
__global__ __launch_bounds__(256) void layer2_kernel(
    const float* __restrict__ h, const float* __restrict__ norm_in,
    const int* __restrict__ row_off, const int* __restrict__ csr_src,
    const float* __restrict__ W2, const float* __restrict__ b2,
    float* __restrict__ out)
{
    __shared__ float Ws[F * F];
    int tid = threadIdx.x;
    for (int i = tid; i < F * F; i += 256) Ws[i] = W2[i];
    __syncthreads();
    int wid = tid >> 6, lane = tid & 63;
    int n = blockIdx.x * 4 + wid;
    if (n >= N_NODES) return;
    int beg = __builtin_amdgcn_readfirstlane(row_off[n]);
    int end = __builtin_amdgcn_readfirstlane(row_off[n + 1]);
    float a0 = 0.f, a1 = 0.f, a2 = 0.f, a3 = 0.f;
    int i = beg;
    for (; i + 4 <= end; i += 4) {
        int s0 = __builtin_amdgcn_readfirstlane(csr_src[i]);
        int s1 = __builtin_amdgcn_readfirstlane(csr_src[i + 1]);
        int s2 = __builtin_amdgcn_readfirstlane(csr_src[i + 2]);
        int s3 = __builtin_amdgcn_readfirstlane(csr_src[i + 3]);
        a0 += h[s0 * F + lane];
        a1 += h[s1 * F + lane];
        a2 += h[s2 * F + lane];
        a3 += h[s3 * F + lane];
    }
    for (; i < end; ++i) {
        int s0 = __builtin_amdgcn_readfirstlane(csr_src[i]);
        a0 += h[s0 * F + lane];
    }
    float agg = (a0 + a1) + (a2 + a3);
    float acc = 0.f;
    #pragma unroll
    for (int k = 0; k < F; ++k) {
        float ak = __shfl(agg, k, 64);
        acc += ak * Ws[k * F + lane];
    }
    float z = acc * norm_in[n] + b2[lane];
    // out[:, f+32] = -y[:, f] (f<32);  out[:, f-32] = +y[:, f] (f>=32)
    int oc = (lane + 32) & 63;
    float sgn = (lane < 32) ? -1.f : 1.f;
    out[n * F + oc] = sgn * z;
}

extern "C" void kernel_launch(void* const* d_in, const int* in_sizes, int n_in,
                              void* d_out, int out_size, void* d_ws, size_t ws_size,
                              hipStream_t stream) {
    const float* x   = (const float*)d_in[0];
    const int*   src = (const int*)d_in[1];
    const int*   dst = (const int*)d_in[2];
    const float* W1  = (const float*)d_in[3];
    const float* b1  = (const float*)d_in[4];
    const float* W2  = (const float*)d_in[5];
    const float* b2  = (const float*)d_in[6];
    float* out = (float*)d_out;

    // ws layout (all 4-byte elements)
    unsigned* deg_out_u = (unsigned*)d_ws;            // NPAD
    unsigned* deg_in_u  = deg_out_u + NPAD;           // NPAD
    unsigned* cursor    = deg_in_u + NPAD;            // NPAD
    float*    norm_out  = (float*)(cursor + NPAD);    // NPAD
    float*    norm_in   = norm_out + NPAD;            // NPAD
    int*      row_off   = (int*)(norm_in + NPAD);     // NPAD (N_NODES+1 used)
    int*      csr_src   = row_off + NPAD;             // N_EDGES
    float*    buf_h     = (float*)(csr_src + N_EDGES);// N_NODES*F

    // zero the three atomic-counter arrays (contiguous)
    hipMemsetAsync(deg_out_u, 0, 3 * NPAD * sizeof(unsigned), stream);

    degrees_kernel<<<(N_EDGES + 255) / 256, 256, 0, stream>>>(src, dst, deg_out_u, deg_in_u);
    norms_kernel<<<(N_NODES + 255) / 256, 256, 0, stream>>>(deg_out_u, deg_in_u, norm_out, norm_in);
    scan_kernel<<<1, 1024, 0, stream>>>(deg_in_u, row_off);
    csr_fill_kernel<<<(N_EDGES + 255) / 256, 256, 0, stream>>>(src, dst, row_off, cursor, csr_src);

    layer1_kernel<<<(N_NODES + 3) / 4, 256, 0, stream>>>(
        x, norm_out, norm_in, row_off, csr_src, W1, b1, buf_h);
    layer2_kernel<<<(N_NODES + 3) / 4, 256, 0, stream>>>(
        buf_h, norm_in, row_off, csr_src, W2, b2, out);
}

// Round 3
// 340.854 us; speedup vs baseline: 1.6713x; 1.1962x over previous
//
#include <hip/hip_runtime.h>
#include <hip/hip_bf16.h>
#include <math.h>

#define N_NODES 50000
#define N_EDGES 800000
#define F 64
#define NPAD 50048                 // padded per-array stride in ws
#define NBLK ((N_NODES + 255) / 256)   // 196 scan blocks

// ---------------- degree histogram (int atomics) ----------------
__global__ __launch_bounds__(256) void degrees_kernel(
    const int* __restrict__ src, const int* __restrict__ dst,
    unsigned* __restrict__ deg_out_u, unsigned* __restrict__ deg_in_u)
{
    int e = blockIdx.x * 256 + threadIdx.x;
    if (e < N_EDGES) {
        atomicAdd(&deg_out_u[src[e]], 1u);
        atomicAdd(&deg_in_u[dst[e]], 1u);
    }
}

__device__ inline unsigned wave_incl_scan(unsigned v, int lane) {
    #pragma unroll
    for (int d = 1; d < 64; d <<= 1) {
        unsigned u = __shfl_up(v, d, 64);
        if (lane >= d) v += u;
    }
    return v;
}

// ---------------- scan phase A: block-local exclusive scan + norms ----------------
__global__ __launch_bounds__(256) void scan_a_kernel(
    const unsigned* __restrict__ deg_in_u, const unsigned* __restrict__ deg_out_u,
    float* __restrict__ norm_out, float* __restrict__ norm_in,
    int* __restrict__ row_off, unsigned* __restrict__ blockSums)
{
    __shared__ unsigned wsum[4];
    int t = threadIdx.x, b = blockIdx.x;
    int idx = b * 256 + t;
    unsigned v = 0, dout = 0;
    if (idx < N_NODES) { v = deg_in_u[idx]; dout = deg_out_u[idx]; }
    int lane = t & 63, wid = t >> 6;
    unsigned inc = wave_incl_scan(v, lane);
    if (lane == 63) wsum[wid] = inc;
    __syncthreads();
    if (t == 0) {
        unsigned acc = 0;
        #pragma unroll
        for (int w = 0; w < 4; ++w) { unsigned x = wsum[w]; wsum[w] = acc; acc += x; }
    }
    __syncthreads();
    unsigned excl = inc - v + wsum[wid];
    if (idx < N_NODES) {
        row_off[idx] = (int)excl;
        norm_in[idx]  = v    ? rsqrtf((float)v)    : 0.f;
        norm_out[idx] = dout ? rsqrtf((float)dout) : 0.f;
    }
    if (t == 255) blockSums[b] = excl + v;
}

// ---------------- scan phase B: scan the 196 block sums ----------------
__global__ __launch_bounds__(256) void scan_b_kernel(
    const unsigned* __restrict__ blockSums, unsigned* __restrict__ blockOff)
{
    __shared__ unsigned wsum[4];
    int t = threadIdx.x;
    unsigned v = (t < NBLK) ? blockSums[t] : 0u;
    int lane = t & 63, wid = t >> 6;
    unsigned inc = wave_incl_scan(v, lane);
    if (lane == 63) wsum[wid] = inc;
    __syncthreads();
    if (t == 0) {
        unsigned acc = 0;
        #pragma unroll
        for (int w = 0; w < 4; ++w) { unsigned x = wsum[w]; wsum[w] = acc; acc += x; }
    }
    __syncthreads();
    if (t < NBLK) blockOff[t] = inc - v + wsum[wid];
}

// ---------------- scan phase C: add block offsets; init cursor ----------------
__global__ __launch_bounds__(256) void scan_c_kernel(
    const unsigned* __restrict__ blockOff, int* __restrict__ row_off,
    unsigned* __restrict__ cursor)
{
    int idx = blockIdx.x * 256 + threadIdx.x;
    if (idx < N_NODES) {
        int v = row_off[idx] + (int)blockOff[blockIdx.x];
        row_off[idx] = v;
        cursor[idx] = (unsigned)v;     // absolute cursor for csr_fill
    }
    if (idx == 0) row_off[N_NODES] = N_EDGES;
}

// ---------------- bucket fill: one atomic -> absolute slot ----------------
__global__ __launch_bounds__(256) void csr_fill_kernel(
    const int* __restrict__ src, const int* __restrict__ dst,
    unsigned* __restrict__ cursor, int* __restrict__ csr_src)
{
    int e = blockIdx.x * 256 + threadIdx.x;
    if (e < N_EDGES) {
        unsigned p = atomicAdd(&cursor[dst[e]], 1u);
        csr_src[p] = src[e];
    }
}

// ---------------- fused layer 1: aggregate + GEMM + tanh + pre-scale ----------------
__global__ __launch_bounds__(256) void layer1_kernel(
    const float* __restrict__ x, const float* __restrict__ norm_out,
    const float* __restrict__ norm_in, const int* __restrict__ row_off,
    const int* __restrict__ csr_src, const float* __restrict__ W1,
    const float* __restrict__ b1, float* __restrict__ h)
{
    __shared__ float Ws[F * F];
    int tid = threadIdx.x;
    for (int i = tid; i < F * F; i += 256) Ws[i] = W1[i];
    __syncthreads();
    int wid = tid >> 6, lane = tid & 63;
    int n = blockIdx.x * 4 + wid;
    if (n >= N_NODES) return;
    int beg = __builtin_amdgcn_readfirstlane(row_off[n]);
    int end = __builtin_amdgcn_readfirstlane(row_off[n + 1]);
    float a0 = 0.f, a1 = 0.f, a2 = 0.f, a3 = 0.f;
    int i = beg;
    for (; i + 4 <= end; i += 4) {
        int s0 = __builtin_amdgcn_readfirstlane(csr_src[i]);
        int s1 = __builtin_amdgcn_readfirstlane(csr_src[i + 1]);
        int s2 = __builtin_amdgcn_readfirstlane(csr_src[i + 2]);
        int s3 = __builtin_amdgcn_readfirstlane(csr_src[i + 3]);
        float w0 = norm_out[s0], w1 = norm_out[s1], w2 = norm_out[s2], w3 = norm_out[s3];
        a0 += x[s0 * F + lane] * w0;
        a1 += x[s1 * F + lane] * w1;
        a2 += x[s2 * F + lane] * w2;
        a3 += x[s3 * F + lane] * w3;
    }
    for (; i < end; ++i) {
        int s0 = __builtin_amdgcn_readfirstlane(csr_src[i]);
        a0 += x[s0 * F + lane] * norm_out[s0];
    }
    float agg = (a0 + a1) + (a2 + a3);
    float acc = 0.f;
    #pragma unroll
    for (int k = 0; k < F; ++k) {
        float ak = __shfl(agg, k, 64);
        acc += ak * Ws[k * F + lane];
    }
    float z = tanhf(acc * norm_in[n] + b1[lane]);
    h[n * F + lane] = z * norm_out[n];   // pre-scale for layer-2 source side
}

// ---------------- fused layer 2: aggregate + GEMM + J^T fold ----------------
__global__ __launch_bounds__(256) void layer2_kernel(
    const float* __restrict__ h, const float* __restrict__ norm_in,
    const int* __restrict__ row_off, const int* __restrict__ csr_src,
    const float* __restrict__ W2, const float* __restrict__ b2,
    float* __restrict__ out)
{
    __shared__ float Ws[F * F];
    int tid = threadIdx.x;
    for (int i = tid; i < F * F; i += 256) Ws[i] = W2[i];
    __syncthreads();
    int wid = tid >> 6, lane = tid & 63;
    int n = blockIdx.x * 4 + wid;
    if (n >= N_NODES) return;
    int beg = __builtin_amdgcn_readfirstlane(row_off[n]);
    int end = __builtin_amdgcn_readfirstlane(row_off[n + 1]);
    float a0 = 0.f, a1 = 0.f, a2 = 0.f, a3 = 0.f;
    int i = beg;
    for (; i + 4 <= end; i += 4) {
        int s0 = __builtin_amdgcn_readfirstlane(csr_src[i]);
        int s1 = __builtin_amdgcn_readfirstlane(csr_src[i + 1]);
        int s2 = __builtin_amdgcn_readfirstlane(csr_src[i + 2]);
        int s3 = __builtin_amdgcn_readfirstlane(csr_src[i + 3]);
        a0 += h[s0 * F + lane];
        a1 += h[s1 * F + lane];
        a2 += h[s2 * F + lane];
        a3 += h[s3 * F + lane];
    }
    for (; i < end; ++i) {
        int s0 = __builtin_amdgcn_readfirstlane(csr_src[i]);
        a0 += h[s0 * F + lane];
    }
    float agg = (a0 + a1) + (a2 + a3);
    float acc = 0.f;
    #pragma unroll
    for (int k = 0; k < F; ++k) {
        float ak = __shfl(agg, k, 64);
        acc += ak * Ws[k * F + lane];
    }
    float z = acc * norm_in[n] + b2[lane];
    int oc = (lane + 32) & 63;
    float sgn = (lane < 32) ? -1.f : 1.f;
    out[n * F + oc] = sgn * z;
}

extern "C" void kernel_launch(void* const* d_in, const int* in_sizes, int n_in,
                              void* d_out, int out_size, void* d_ws, size_t ws_size,
                              hipStream_t stream) {
    const float* x   = (const float*)d_in[0];
    const int*   src = (const int*)d_in[1];
    const int*   dst = (const int*)d_in[2];
    const float* W1  = (const float*)d_in[3];
    const float* b1  = (const float*)d_in[4];
    const float* W2  = (const float*)d_in[5];
    const float* b2  = (const float*)d_in[6];
    float* out = (float*)d_out;

    // ws layout (4-byte elements)
    unsigned* deg_out_u = (unsigned*)d_ws;             // NPAD
    unsigned* deg_in_u  = deg_out_u + NPAD;            // NPAD
    unsigned* cursor    = deg_in_u + NPAD;             // NPAD
    float*    norm_out  = (float*)(cursor + NPAD);     // NPAD
    float*    norm_in   = norm_out + NPAD;             // NPAD
    int*      row_off   = (int*)(norm_in + NPAD);      // NPAD (N_NODES+1 used)
    int*      csr_src   = row_off + NPAD;              // N_EDGES
    float*    buf_h     = (float*)(csr_src + N_EDGES); // N_NODES*F
    unsigned* blockSums = (unsigned*)(buf_h + (size_t)N_NODES * F); // 256
    unsigned* blockOff  = blockSums + 256;             // 256

    // zero only the two degree-histogram arrays (contiguous)
    hipMemsetAsync(deg_out_u, 0, 2 * NPAD * sizeof(unsigned), stream);

    degrees_kernel<<<(N_EDGES + 255) / 256, 256, 0, stream>>>(src, dst, deg_out_u, deg_in_u);
    scan_a_kernel<<<NBLK, 256, 0, stream>>>(deg_in_u, deg_out_u, norm_out, norm_in, row_off, blockSums);
    scan_b_kernel<<<1, 256, 0, stream>>>(blockSums, blockOff);
    scan_c_kernel<<<NBLK, 256, 0, stream>>>(blockOff, row_off, cursor);
    csr_fill_kernel<<<(N_EDGES + 255) / 256, 256, 0, stream>>>(src, dst, cursor, csr_src);

    layer1_kernel<<<(N_NODES + 3) / 4, 256, 0, stream>>>(
        x, norm_out, norm_in, row_off, csr_src, W1, b1, buf_h);
    layer2_kernel<<<(N_NODES + 3) / 4, 256, 0, stream>>>(
        buf_h, norm_in, row_off, csr_src, W2, b2, out);
}

// Round 4
// 292.960 us; speedup vs baseline: 1.9445x; 1.1635x over previous
//
#include <hip/hip_runtime.h>
#include <hip/hip_bf16.h>
#include <math.h>

#define N_NODES 50000
#define N_EDGES 800000
#define F 64
#define NPAD 50048                     // padded per-array stride in ws
#define NBLK ((N_NODES + 255) / 256)   // 196 scan blocks

typedef short short8 __attribute__((ext_vector_type(8)));
typedef float f32x4 __attribute__((ext_vector_type(4)));

// float -> bf16 bits, round-nearest-even
__device__ inline unsigned short f2bf(float f) {
    unsigned u = __float_as_uint(f);
    unsigned r = (u + 0x7fffu + ((u >> 16) & 1u)) >> 16;
    return (unsigned short)r;
}
// bf16 bits (low 16 of v) -> float
__device__ inline float bf2f(unsigned v) { return __uint_as_float(v << 16); }

// ---------------- degree histogram (int atomics) ----------------
__global__ __launch_bounds__(256) void degrees_kernel(
    const int* __restrict__ src, const int* __restrict__ dst,
    unsigned* __restrict__ deg_out_u, unsigned* __restrict__ deg_in_u)
{
    int e = blockIdx.x * 256 + threadIdx.x;
    if (e < N_EDGES) {
        atomicAdd(&deg_out_u[src[e]], 1u);
        atomicAdd(&deg_in_u[dst[e]], 1u);
    }
}

__device__ inline unsigned wave_incl_scan(unsigned v, int lane) {
    #pragma unroll
    for (int d = 1; d < 64; d <<= 1) {
        unsigned u = __shfl_up(v, d, 64);
        if (lane >= d) v += u;
    }
    return v;
}

// ---------------- scan phase A: block-local exclusive scan + norms ----------------
__global__ __launch_bounds__(256) void scan_a_kernel(
    const unsigned* __restrict__ deg_in_u, const unsigned* __restrict__ deg_out_u,
    float* __restrict__ norm_out, float* __restrict__ norm_in,
    int* __restrict__ row_off, unsigned* __restrict__ blockSums)
{
    __shared__ unsigned wsum[4];
    int t = threadIdx.x, b = blockIdx.x;
    int idx = b * 256 + t;
    unsigned v = 0, dout = 0;
    if (idx < N_NODES) { v = deg_in_u[idx]; dout = deg_out_u[idx]; }
    int lane = t & 63, wid = t >> 6;
    unsigned inc = wave_incl_scan(v, lane);
    if (lane == 63) wsum[wid] = inc;
    __syncthreads();
    if (t == 0) {
        unsigned acc = 0;
        #pragma unroll
        for (int w = 0; w < 4; ++w) { unsigned x = wsum[w]; wsum[w] = acc; acc += x; }
    }
    __syncthreads();
    unsigned excl = inc - v + wsum[wid];
    if (idx < N_NODES) {
        row_off[idx] = (int)excl;
        norm_in[idx]  = v    ? rsqrtf((float)v)    : 0.f;
        norm_out[idx] = dout ? rsqrtf((float)dout) : 0.f;
    }
    if (t == 255) blockSums[b] = excl + v;
}

// ---------------- scan phase B: scan the 196 block sums ----------------
__global__ __launch_bounds__(256) void scan_b_kernel(
    const unsigned* __restrict__ blockSums, unsigned* __restrict__ blockOff)
{
    __shared__ unsigned wsum[4];
    int t = threadIdx.x;
    unsigned v = (t < NBLK) ? blockSums[t] : 0u;
    int lane = t & 63, wid = t >> 6;
    unsigned inc = wave_incl_scan(v, lane);
    if (lane == 63) wsum[wid] = inc;
    __syncthreads();
    if (t == 0) {
        unsigned acc = 0;
        #pragma unroll
        for (int w = 0; w < 4; ++w) { unsigned x = wsum[w]; wsum[w] = acc; acc += x; }
    }
    __syncthreads();
    if (t < NBLK) blockOff[t] = inc - v + wsum[wid];
}

// ---------------- scan phase C: add block offsets; init cursor ----------------
__global__ __launch_bounds__(256) void scan_c_kernel(
    const unsigned* __restrict__ blockOff, int* __restrict__ row_off,
    unsigned* __restrict__ cursor)
{
    int idx = blockIdx.x * 256 + threadIdx.x;
    if (idx < N_NODES) {
        int v = row_off[idx] + (int)blockOff[blockIdx.x];
        row_off[idx] = v;
        cursor[idx] = (unsigned)v;
    }
    if (idx == 0) row_off[N_NODES] = N_EDGES;
}

// ---------------- bucket fill: one atomic -> absolute slot ----------------
__global__ __launch_bounds__(256) void csr_fill_kernel(
    const int* __restrict__ src, const int* __restrict__ dst,
    unsigned* __restrict__ cursor, int* __restrict__ csr_src)
{
    int e = blockIdx.x * 256 + threadIdx.x;
    if (e < N_EDGES) {
        unsigned p = atomicAdd(&cursor[dst[e]], 1u);
        csr_src[p] = src[e];
    }
}

// ---------------- prescale: xb = bf16(x * norm_out), packed 2 feats/uint ----------------
__global__ __launch_bounds__(256) void prescale_kernel(
    const float* __restrict__ x, const float* __restrict__ norm_out,
    unsigned* __restrict__ xb)
{
    int t = blockIdx.x * 256 + threadIdx.x;   // one uint = 2 features
    if (t < N_NODES * 32) {
        int n = t >> 5;
        float w = norm_out[n];
        float2 v = ((const float2*)x)[t];
        xb[t] = (unsigned)f2bf(v.x * w) | ((unsigned)f2bf(v.y * w) << 16);
    }
}

// ---------------- aggregation: wave/node, 2 edges per iter (half-wave each) ----------
// tab rows are pre-scaled bf16 [64 feats = 32 uints]; output aggb scaled by norm_in.
__global__ __launch_bounds__(256) void agg_kernel(
    const unsigned* __restrict__ tab, const float* __restrict__ norm_in,
    const int* __restrict__ row_off, const int* __restrict__ csr_src,
    unsigned* __restrict__ aggb)
{
    int tid = threadIdx.x;
    int wid = tid >> 6, lane = tid & 63;
    int n = blockIdx.x * 4 + wid;
    if (n >= N_NODES) return;
    int beg = __builtin_amdgcn_readfirstlane(row_off[n]);
    int end = __builtin_amdgcn_readfirstlane(row_off[n + 1]);
    int lp = lane & 31;
    float ax = 0.f, ay = 0.f;
    for (int i = beg; i < end; i += 2) {
        int s0 = __builtin_amdgcn_readfirstlane(csr_src[i]);
        int s1 = (i + 1 < end) ? __builtin_amdgcn_readfirstlane(csr_src[i + 1]) : -1;
        int s = (lane < 32) ? s0 : s1;
        if (s >= 0) {
            unsigned v = tab[s * 32 + lp];
            ax += bf2f(v & 0xffffu);
            ay += bf2f(v >> 16);
        }
    }
    ax += __shfl_xor(ax, 32);
    ay += __shfl_xor(ay, 32);
    if (lane < 32) {
        float w = norm_in[n];
        aggb[n * 32 + lp] = (unsigned)f2bf(ax * w) | ((unsigned)f2bf(ay * w) << 16);
    }
}

// ---------------- MFMA GEMM layer 1: H = bf16( tanh(AGG@W1 + b1) * norm_out ) -------
// wave handles 16 rows x 64 cols; A frag: A[m=lane&15][k=quad*8+j]; C/D: col=lane&15,
// row=quad*4+reg (m89/m120-verified layouts).
__global__ __launch_bounds__(256) void gemm1_mfma_kernel(
    const unsigned short* __restrict__ aggb, const float* __restrict__ W1,
    const float* __restrict__ b1, const float* __restrict__ norm_out,
    unsigned short* __restrict__ hb)
{
    int tid = threadIdx.x;
    int wid = tid >> 6, lane = tid & 63;
    int col = lane & 15, quad = lane >> 4;
    int m0 = blockIdx.x * 64 + wid * 16;

    short8 bfrag[2][4];
    #pragma unroll
    for (int kt = 0; kt < 2; ++kt)
        #pragma unroll
        for (int nt = 0; nt < 4; ++nt)
            #pragma unroll
            for (int j = 0; j < 8; ++j)
                bfrag[kt][nt][j] = (short)f2bf(W1[(kt * 32 + quad * 8 + j) * F + nt * 16 + col]);

    short8 afrag[2];
    #pragma unroll
    for (int kt = 0; kt < 2; ++kt)
        afrag[kt] = *(const short8*)(aggb + (size_t)(m0 + col) * F + kt * 32 + quad * 8);

    f32x4 acc[4];
    #pragma unroll
    for (int nt = 0; nt < 4; ++nt) acc[nt] = (f32x4){0.f, 0.f, 0.f, 0.f};
    #pragma unroll
    for (int kt = 0; kt < 2; ++kt)
        #pragma unroll
        for (int nt = 0; nt < 4; ++nt)
            acc[nt] = __builtin_amdgcn_mfma_f32_16x16x32_bf16(afrag[kt], bfrag[kt][nt], acc[nt], 0, 0, 0);

    #pragma unroll
    for (int r = 0; r < 4; ++r) {
        int row = m0 + quad * 4 + r;
        if (row < N_NODES) {
            float w = norm_out[row];
            #pragma unroll
            for (int nt = 0; nt < 4; ++nt) {
                float z = tanhf(acc[nt][r] + b1[nt * 16 + col]) * w;
                hb[(size_t)row * F + nt * 16 + col] = f2bf(z);
            }
        }
    }
}

// ---------------- MFMA GEMM layer 2 + J^T fold: out fp32 ----------------
__global__ __launch_bounds__(256) void gemm2_mfma_kernel(
    const unsigned short* __restrict__ aggb, const float* __restrict__ W2,
    const float* __restrict__ b2, float* __restrict__ out)
{
    int tid = threadIdx.x;
    int wid = tid >> 6, lane = tid & 63;
    int col = lane & 15, quad = lane >> 4;
    int m0 = blockIdx.x * 64 + wid * 16;

    short8 bfrag[2][4];
    #pragma unroll
    for (int kt = 0; kt < 2; ++kt)
        #pragma unroll
        for (int nt = 0; nt < 4; ++nt)
            #pragma unroll
            for (int j = 0; j < 8; ++j)
                bfrag[kt][nt][j] = (short)f2bf(W2[(kt * 32 + quad * 8 + j) * F + nt * 16 + col]);

    short8 afrag[2];
    #pragma unroll
    for (int kt = 0; kt < 2; ++kt)
        afrag[kt] = *(const short8*)(aggb + (size_t)(m0 + col) * F + kt * 32 + quad * 8);

    f32x4 acc[4];
    #pragma unroll
    for (int nt = 0; nt < 4; ++nt) acc[nt] = (f32x4){0.f, 0.f, 0.f, 0.f};
    #pragma unroll
    for (int kt = 0; kt < 2; ++kt)
        #pragma unroll
        for (int nt = 0; nt < 4; ++nt)
            acc[nt] = __builtin_amdgcn_mfma_f32_16x16x32_bf16(afrag[kt], bfrag[kt][nt], acc[nt], 0, 0, 0);

    #pragma unroll
    for (int r = 0; r < 4; ++r) {
        int row = m0 + quad * 4 + r;
        if (row < N_NODES) {
            #pragma unroll
            for (int nt = 0; nt < 4; ++nt) {
                int nn = nt * 16 + col;
                float z = acc[nt][r] + b2[nn];
                int oc = (nn + 32) & 63;
                float sgn = (nn < 32) ? -1.f : 1.f;
                out[(size_t)row * F + oc] = sgn * z;
            }
        }
    }
}

extern "C" void kernel_launch(void* const* d_in, const int* in_sizes, int n_in,
                              void* d_out, int out_size, void* d_ws, size_t ws_size,
                              hipStream_t stream) {
    const float* x   = (const float*)d_in[0];
    const int*   src = (const int*)d_in[1];
    const int*   dst = (const int*)d_in[2];
    const float* W1  = (const float*)d_in[3];
    const float* b1  = (const float*)d_in[4];
    const float* W2  = (const float*)d_in[5];
    const float* b2  = (const float*)d_in[6];
    float* out = (float*)d_out;

    // ws layout (4-byte units)
    unsigned* deg_out_u = (unsigned*)d_ws;              // NPAD
    unsigned* deg_in_u  = deg_out_u + NPAD;             // NPAD
    unsigned* cursor    = deg_in_u + NPAD;              // NPAD
    float*    norm_out  = (float*)(cursor + NPAD);      // NPAD
    float*    norm_in   = norm_out + NPAD;              // NPAD
    int*      row_off   = (int*)(norm_in + NPAD);       // NPAD
    int*      csr_src   = row_off + NPAD;               // N_EDGES
    unsigned* xb        = (unsigned*)(csr_src + N_EDGES); // NPAD*32 (bf16 table; reused as hb)
    unsigned* aggb      = xb + (size_t)NPAD * 32;       // NPAD*32
    unsigned* blockSums = aggb + (size_t)NPAD * 32;     // 256
    unsigned* blockOff  = blockSums + 256;              // 256

    hipMemsetAsync(deg_out_u, 0, 2 * NPAD * sizeof(unsigned), stream);

    degrees_kernel<<<(N_EDGES + 255) / 256, 256, 0, stream>>>(src, dst, deg_out_u, deg_in_u);
    scan_a_kernel<<<NBLK, 256, 0, stream>>>(deg_in_u, deg_out_u, norm_out, norm_in, row_off, blockSums);
    scan_b_kernel<<<1, 256, 0, stream>>>(blockSums, blockOff);
    scan_c_kernel<<<NBLK, 256, 0, stream>>>(blockOff, row_off, cursor);
    csr_fill_kernel<<<(N_EDGES + 255) / 256, 256, 0, stream>>>(src, dst, cursor, csr_src);

    // layer 1
    prescale_kernel<<<(N_NODES * 32 + 255) / 256, 256, 0, stream>>>(x, norm_out, xb);
    agg_kernel<<<(N_NODES + 3) / 4, 256, 0, stream>>>(xb, norm_in, row_off, csr_src, aggb);
    gemm1_mfma_kernel<<<(N_NODES + 63) / 64, 256, 0, stream>>>(
        (const unsigned short*)aggb, W1, b1, norm_out, (unsigned short*)xb);  // hb aliases xb

    // layer 2
    agg_kernel<<<(N_NODES + 3) / 4, 256, 0, stream>>>(xb, norm_in, row_off, csr_src, aggb);
    gemm2_mfma_kernel<<<(N_NODES + 63) / 64, 256, 0, stream>>>(
        (const unsigned short*)aggb, W2, b2, out);
}

// Round 6
// 258.163 us; speedup vs baseline: 2.2066x; 1.1348x over previous
//
#include <hip/hip_runtime.h>
#include <hip/hip_bf16.h>
#include <math.h>

#define N_NODES 50000
#define N_EDGES 800000
#define F 64
#define NPAD 50048                     // padded per-array stride in ws
#define NBLK ((N_NODES + 255) / 256)   // 196 (fallback scan blocks)

// ---- LDS counting-sort parameters ----
#define P_HIST 128
#define CHUNK (N_EDGES / P_HIST)       // 6250 (exact)
#define WORDS 25000                    // 50000 bins, 2 u16 counters per u32 word
#define RP0W 16000                     // words in range-pass 0 (bins 0..31999) -> 64000 B LDS
#define RP1W (WORDS - RP0W)            // 9000 words (bins 32000..49999)
#define RBLK ((WORDS + 255) / 256)     // 98 reduce blocks

typedef short short8 __attribute__((ext_vector_type(8)));
typedef float f32x4 __attribute__((ext_vector_type(4)));

// float -> bf16 bits, round-nearest-even
__device__ inline unsigned short f2bf(float f) {
    unsigned u = __float_as_uint(f);
    unsigned r = (u + 0x7fffu + ((u >> 16) & 1u)) >> 16;
    return (unsigned short)r;
}
// bf16 bits (low 16 of v) -> float
__device__ inline float bf2f(unsigned v) { return __uint_as_float(v << 16); }

__device__ inline unsigned wave_incl_scan(unsigned v, int lane) {
    #pragma unroll
    for (int d = 1; d < 64; d <<= 1) {
        unsigned u = __shfl_up(v, d, 64);
        if (lane >= d) v += u;
    }
    return v;
}

// =============== build phase (atomic-free, LDS-privatized) ===============

// per-block packed-u16 histograms of dst and src over this block's edge chunk
__global__ __launch_bounds__(256) void hist_kernel(
    const int* __restrict__ src, const int* __restrict__ dst,
    unsigned* __restrict__ histd, unsigned* __restrict__ hists)
{
    __shared__ unsigned lds[RP0W];
    int p = blockIdx.x, t = threadIdx.x;
    int e0 = p * CHUNK;
    for (int hp = 0; hp < 2; ++hp) {
        const int* col = hp ? src : dst;
        unsigned* outp = (hp ? hists : histd) + (size_t)p * WORDS;
        for (int rp = 0; rp < 2; ++rp) {
            int wbase = rp ? RP0W : 0;
            int nw    = rp ? RP1W : RP0W;
            int bin_lo = wbase * 2, bin_hi = bin_lo + nw * 2;
            for (int i = t; i < nw; i += 256) lds[i] = 0;
            __syncthreads();
            for (int i = t; i < CHUNK; i += 256) {
                int v = col[e0 + i];
                if (v >= bin_lo && v < bin_hi)
                    atomicAdd(&lds[(v >> 1) - wbase], 1u << ((v & 1) * 16));
            }
            __syncthreads();
            for (int i = t; i < nw; i += 256) outp[wbase + i] = lds[i];
            __syncthreads();
        }
    }
}

// sum partials -> degrees -> norms; overwrite histd with per-block exclusive
// prefixes (packed u16, bounded by per-node degree); block-scan for row_off.
__global__ __launch_bounds__(256) void reduce_kernel(
    unsigned* __restrict__ histd, const unsigned* __restrict__ hists,
    float* __restrict__ norm_in, float* __restrict__ norm_out,
    int* __restrict__ row_off, unsigned* __restrict__ blockSums)
{
    __shared__ unsigned wsum[4];
    int t = threadIdx.x, b = blockIdx.x;
    int w = b * 256 + t;
    unsigned s0 = 0, s1 = 0, t0 = 0, t1 = 0;
    if (w < WORDS) {
        for (int p = 0; p < P_HIST; ++p) {
            size_t idx = (size_t)p * WORDS + w;
            unsigned vd = histd[idx];
            histd[idx] = s0 | (s1 << 16);      // exclusive prefix across blocks
            s0 += vd & 0xffffu; s1 += vd >> 16;
            unsigned vs = hists[idx];
            t0 += vs & 0xffffu; t1 += vs >> 16;
        }
        norm_in[2 * w]      = s0 ? rsqrtf((float)s0) : 0.f;
        norm_in[2 * w + 1]  = s1 ? rsqrtf((float)s1) : 0.f;
        norm_out[2 * w]     = t0 ? rsqrtf((float)t0) : 0.f;
        norm_out[2 * w + 1] = t1 ? rsqrtf((float)t1) : 0.f;
    }
    unsigned pairsum = s0 + s1;
    int lane = t & 63, wid = t >> 6;
    unsigned inc = wave_incl_scan(pairsum, lane);
    if (lane == 63) wsum[wid] = inc;
    __syncthreads();
    if (t == 0) {
        unsigned acc = 0;
        #pragma unroll
        for (int q = 0; q < 4; ++q) { unsigned x = wsum[q]; wsum[q] = acc; acc += x; }
    }
    __syncthreads();
    unsigned excl = inc - pairsum + wsum[wid];
    if (w < WORDS) {
        row_off[2 * w]     = (int)excl;
        row_off[2 * w + 1] = (int)(excl + s0);
    }
    if (t == 255) blockSums[b] = excl + pairsum;
}

// generic small scan: cnt <= 256 block sums -> exclusive offsets
__global__ __launch_bounds__(256) void scan_b_kernel(
    const unsigned* __restrict__ blockSums, unsigned* __restrict__ blockOff, int cnt)
{
    __shared__ unsigned wsum[4];
    int t = threadIdx.x;
    unsigned v = (t < cnt) ? blockSums[t] : 0u;
    int lane = t & 63, wid = t >> 6;
    unsigned inc = wave_incl_scan(v, lane);
    if (lane == 63) wsum[wid] = inc;
    __syncthreads();
    if (t == 0) {
        unsigned acc = 0;
        #pragma unroll
        for (int q = 0; q < 4; ++q) { unsigned x = wsum[q]; wsum[q] = acc; acc += x; }
    }
    __syncthreads();
    if (t < cnt) blockOff[t] = inc - v + wsum[wid];
}

// add block offsets to row_off (RBLK grid, 2 bins/thread)
__global__ __launch_bounds__(256) void scan_c2_kernel(
    const unsigned* __restrict__ blockOff, int* __restrict__ row_off)
{
    int t = threadIdx.x, b = blockIdx.x;
    int w = b * 256 + t;
    if (w < WORDS) {
        int off = (int)blockOff[b];
        row_off[2 * w] += off;
        row_off[2 * w + 1] += off;
    }
    if (w == 0) row_off[N_NODES] = N_EDGES;
}

// counting-sort scatter: LDS cursor gives local rank; prefix gives block base.
__global__ __launch_bounds__(256) void scatter_kernel(
    const int* __restrict__ src, const int* __restrict__ dst,
    const int* __restrict__ row_off, const unsigned* __restrict__ histd,
    int* __restrict__ csr_src)
{
    __shared__ unsigned lds[RP0W];
    int p = blockIdx.x, t = threadIdx.x;
    int e0 = p * CHUNK;
    const unsigned* pref = histd + (size_t)p * WORDS;
    for (int rp = 0; rp < 2; ++rp) {
        int wbase = rp ? RP0W : 0;
        int nw    = rp ? RP1W : RP0W;
        int bin_lo = wbase * 2, bin_hi = bin_lo + nw * 2;
        for (int i = t; i < nw; i += 256) lds[i] = 0;
        __syncthreads();
        for (int i = t; i < CHUNK; i += 256) {
            int d = dst[e0 + i];
            if (d >= bin_lo && d < bin_hi) {
                int sh = (d & 1) * 16;
                unsigned old = atomicAdd(&lds[(d >> 1) - wbase], 1u << sh);
                unsigned rank = (old >> sh) & 0xffffu;
                unsigned pre  = (pref[d >> 1] >> sh) & 0xffffu;
                csr_src[row_off[d] + (int)(pre + rank)] = src[e0 + i];
            }
        }
        __syncthreads();
    }
}

// =============== fallback build phase (Round-3 style, global atomics) ===============

__global__ __launch_bounds__(256) void degrees_kernel(
    const int* __restrict__ src, const int* __restrict__ dst,
    unsigned* __restrict__ deg_out_u, unsigned* __restrict__ deg_in_u)
{
    int e = blockIdx.x * 256 + threadIdx.x;
    if (e < N_EDGES) {
        atomicAdd(&deg_out_u[src[e]], 1u);
        atomicAdd(&deg_in_u[dst[e]], 1u);
    }
}

__global__ __launch_bounds__(256) void fb_scan_a_kernel(
    const unsigned* __restrict__ deg_in_u, const unsigned* __restrict__ deg_out_u,
    float* __restrict__ norm_out, float* __restrict__ norm_in,
    int* __restrict__ row_off, unsigned* __restrict__ blockSums)
{
    __shared__ unsigned wsum[4];
    int t = threadIdx.x, b = blockIdx.x;
    int idx = b * 256 + t;
    unsigned v = 0, dout = 0;
    if (idx < N_NODES) { v = deg_in_u[idx]; dout = deg_out_u[idx]; }
    int lane = t & 63, wid = t >> 6;
    unsigned inc = wave_incl_scan(v, lane);
    if (lane == 63) wsum[wid] = inc;
    __syncthreads();
    if (t == 0) {
        unsigned acc = 0;
        #pragma unroll
        for (int q = 0; q < 4; ++q) { unsigned x = wsum[q]; wsum[q] = acc; acc += x; }
    }
    __syncthreads();
    unsigned excl = inc - v + wsum[wid];
    if (idx < N_NODES) {
        row_off[idx] = (int)excl;
        norm_in[idx]  = v    ? rsqrtf((float)v)    : 0.f;
        norm_out[idx] = dout ? rsqrtf((float)dout) : 0.f;
    }
    if (t == 255) blockSums[b] = excl + v;
}

__global__ __launch_bounds__(256) void fb_scan_c_kernel(
    const unsigned* __restrict__ blockOff, int* __restrict__ row_off,
    unsigned* __restrict__ cursor)
{
    int idx = blockIdx.x * 256 + threadIdx.x;
    if (idx < N_NODES) {
        int v = row_off[idx] + (int)blockOff[blockIdx.x];
        row_off[idx] = v;
        cursor[idx] = (unsigned)v;
    }
    if (idx == 0) row_off[N_NODES] = N_EDGES;
}

__global__ __launch_bounds__(256) void fb_csr_fill_kernel(
    const int* __restrict__ src, const int* __restrict__ dst,
    unsigned* __restrict__ cursor, int* __restrict__ csr_src)
{
    int e = blockIdx.x * 256 + threadIdx.x;
    if (e < N_EDGES) {
        unsigned p = atomicAdd(&cursor[dst[e]], 1u);
        csr_src[p] = src[e];
    }
}

// =============== layer phase ===============

__global__ __launch_bounds__(256) void prescale_kernel(
    const float* __restrict__ x, const float* __restrict__ norm_out,
    unsigned* __restrict__ xb)
{
    int t = blockIdx.x * 256 + threadIdx.x;   // one uint = 2 features
    if (t < N_NODES * 32) {
        int n = t >> 5;
        float w = norm_out[n];
        float2 v = ((const float2*)x)[t];
        xb[t] = (unsigned)f2bf(v.x * w) | ((unsigned)f2bf(v.y * w) << 16);
    }
}

__global__ __launch_bounds__(256) void agg_kernel(
    const unsigned* __restrict__ tab, const float* __restrict__ norm_in,
    const int* __restrict__ row_off, const int* __restrict__ csr_src,
    unsigned* __restrict__ aggb)
{
    int tid = threadIdx.x;
    int wid = tid >> 6, lane = tid & 63;
    int n = blockIdx.x * 4 + wid;
    if (n >= N_NODES) return;
    int beg = __builtin_amdgcn_readfirstlane(row_off[n]);
    int end = __builtin_amdgcn_readfirstlane(row_off[n + 1]);
    int lp = lane & 31;
    float ax = 0.f, ay = 0.f;
    for (int i = beg; i < end; i += 2) {
        int s0 = __builtin_amdgcn_readfirstlane(csr_src[i]);
        int s1 = (i + 1 < end) ? __builtin_amdgcn_readfirstlane(csr_src[i + 1]) : -1;
        int s = (lane < 32) ? s0 : s1;
        if (s >= 0) {
            unsigned v = tab[s * 32 + lp];
            ax += bf2f(v & 0xffffu);
            ay += bf2f(v >> 16);
        }
    }
    ax += __shfl_xor(ax, 32);
    ay += __shfl_xor(ay, 32);
    if (lane < 32) {
        float w = norm_in[n];
        aggb[n * 32 + lp] = (unsigned)f2bf(ax * w) | ((unsigned)f2bf(ay * w) << 16);
    }
}

__global__ __launch_bounds__(256) void gemm1_mfma_kernel(
    const unsigned short* __restrict__ aggb, const float* __restrict__ Wm,
    const float* __restrict__ bias, const float* __restrict__ norm_out,
    unsigned short* __restrict__ hb)
{
    int tid = threadIdx.x;
    int wid = tid >> 6, lane = tid & 63;
    int col = lane & 15, quad = lane >> 4;
    int m0 = blockIdx.x * 64 + wid * 16;

    short8 bfrag[2][4];
    #pragma unroll
    for (int kt = 0; kt < 2; ++kt)
        #pragma unroll
        for (int nt = 0; nt < 4; ++nt)
            #pragma unroll
            for (int j = 0; j < 8; ++j)
                bfrag[kt][nt][j] = (short)f2bf(Wm[(kt * 32 + quad * 8 + j) * F + nt * 16 + col]);

    short8 afrag[2];
    #pragma unroll
    for (int kt = 0; kt < 2; ++kt)
        afrag[kt] = *(const short8*)(aggb + (size_t)(m0 + col) * F + kt * 32 + quad * 8);

    f32x4 acc[4];
    #pragma unroll
    for (int nt = 0; nt < 4; ++nt) acc[nt] = (f32x4){0.f, 0.f, 0.f, 0.f};
    #pragma unroll
    for (int kt = 0; kt < 2; ++kt)
        #pragma unroll
        for (int nt = 0; nt < 4; ++nt)
            acc[nt] = __builtin_amdgcn_mfma_f32_16x16x32_bf16(afrag[kt], bfrag[kt][nt], acc[nt], 0, 0, 0);

    #pragma unroll
    for (int r = 0; r < 4; ++r) {
        int row = m0 + quad * 4 + r;
        if (row < N_NODES) {
            float w = norm_out[row];
            #pragma unroll
            for (int nt = 0; nt < 4; ++nt) {
                float z = tanhf(acc[nt][r] + bias[nt * 16 + col]) * w;
                hb[(size_t)row * F + nt * 16 + col] = f2bf(z);
            }
        }
    }
}

__global__ __launch_bounds__(256) void gemm2_mfma_kernel(
    const unsigned short* __restrict__ aggb, const float* __restrict__ Wm,
    const float* __restrict__ bias, float* __restrict__ out)
{
    int tid = threadIdx.x;
    int wid = tid >> 6, lane = tid & 63;
    int col = lane & 15, quad = lane >> 4;
    int m0 = blockIdx.x * 64 + wid * 16;

    short8 bfrag[2][4];
    #pragma unroll
    for (int kt = 0; kt < 2; ++kt)
        #pragma unroll
        for (int nt = 0; nt < 4; ++nt)
            #pragma unroll
            for (int j = 0; j < 8; ++j)
                bfrag[kt][nt][j] = (short)f2bf(Wm[(kt * 32 + quad * 8 + j) * F + nt * 16 + col]);

    short8 afrag[2];
    #pragma unroll
    for (int kt = 0; kt < 2; ++kt)
        afrag[kt] = *(const short8*)(aggb + (size_t)(m0 + col) * F + kt * 32 + quad * 8);

    f32x4 acc[4];
    #pragma unroll
    for (int nt = 0; nt < 4; ++nt) acc[nt] = (f32x4){0.f, 0.f, 0.f, 0.f};
    #pragma unroll
    for (int kt = 0; kt < 2; ++kt)
        #pragma unroll
        for (int nt = 0; nt < 4; ++nt)
            acc[nt] = __builtin_amdgcn_mfma_f32_16x16x32_bf16(afrag[kt], bfrag[kt][nt], acc[nt], 0, 0, 0);

    #pragma unroll
    for (int r = 0; r < 4; ++r) {
        int row = m0 + quad * 4 + r;
        if (row < N_NODES) {
            #pragma unroll
            for (int nt = 0; nt < 4; ++nt) {
                int nn = nt * 16 + col;
                float z = acc[nt][r] + bias[nn];
                int oc = (nn + 32) & 63;
                float sgn = (nn < 32) ? -1.f : 1.f;
                out[(size_t)row * F + oc] = sgn * z;
            }
        }
    }
}

extern "C" void kernel_launch(void* const* d_in, const int* in_sizes, int n_in,
                              void* d_out, int out_size, void* d_ws, size_t ws_size,
                              hipStream_t stream) {
    const float* x   = (const float*)d_in[0];
    const int*   src = (const int*)d_in[1];
    const int*   dst = (const int*)d_in[2];
    const float* W1  = (const float*)d_in[3];
    const float* b1  = (const float*)d_in[4];
    const float* W2  = (const float*)d_in[5];
    const float* b2  = (const float*)d_in[6];
    float* out = (float*)d_out;

    // common ws layout (4-byte units)
    unsigned* ws = (unsigned*)d_ws;
    float*    norm_out = (float*)ws;                        // NPAD
    float*    norm_in  = (float*)(ws + NPAD);               // NPAD
    int*      row_off  = (int*)(ws + 2 * NPAD);             // NPAD
    int*      csr_src  = (int*)(ws + 3 * NPAD);             // N_EDGES
    unsigned* xb       = ws + 3 * NPAD + N_EDGES;           // NPAD*32 (bf16 table; reused as hb)
    unsigned* aggb     = xb + (size_t)NPAD * 32;            // NPAD*32
    unsigned* blockSums= aggb + (size_t)NPAD * 32;          // 256
    unsigned* blockOff = blockSums + 256;                   // 256
    unsigned* tail     = blockOff + 256;
    // new path: histd/hists partials
    unsigned* histd = tail;                                 // P_HIST*WORDS
    unsigned* hists = histd + (size_t)P_HIST * WORDS;       // P_HIST*WORDS
    size_t need_new = ((size_t)(tail - ws) + 2 * (size_t)P_HIST * WORDS) * 4;

    if (ws_size >= need_new) {
        hist_kernel<<<P_HIST, 256, 0, stream>>>(src, dst, histd, hists);
        reduce_kernel<<<RBLK, 256, 0, stream>>>(histd, hists, norm_in, norm_out, row_off, blockSums);
        scan_b_kernel<<<1, 256, 0, stream>>>(blockSums, blockOff, RBLK);
        scan_c2_kernel<<<RBLK, 256, 0, stream>>>(blockOff, row_off);
        scatter_kernel<<<P_HIST, 256, 0, stream>>>(src, dst, row_off, histd, csr_src);
    } else {
        // fallback: global-atomic build (aliases partial region)
        unsigned* deg_out_u = tail;
        unsigned* deg_in_u  = tail + NPAD;
        unsigned* cursor    = tail + 2 * NPAD;
        hipMemsetAsync(deg_out_u, 0, 2 * NPAD * sizeof(unsigned), stream);
        degrees_kernel<<<(N_EDGES + 255) / 256, 256, 0, stream>>>(src, dst, deg_out_u, deg_in_u);
        fb_scan_a_kernel<<<NBLK, 256, 0, stream>>>(deg_in_u, deg_out_u, norm_out, norm_in, row_off, blockSums);
        scan_b_kernel<<<1, 256, 0, stream>>>(blockSums, blockOff, NBLK);
        fb_scan_c_kernel<<<NBLK, 256, 0, stream>>>(blockOff, row_off, cursor);
        fb_csr_fill_kernel<<<(N_EDGES + 255) / 256, 256, 0, stream>>>(src, dst, cursor, csr_src);
    }

    // layer 1
    prescale_kernel<<<(N_NODES * 32 + 255) / 256, 256, 0, stream>>>(x, norm_out, xb);
    agg_kernel<<<(N_NODES + 3) / 4, 256, 0, stream>>>(xb, norm_in, row_off, csr_src, aggb);
    gemm1_mfma_kernel<<<(N_NODES + 63) / 64, 256, 0, stream>>>(
        (const unsigned short*)aggb, W1, b1, norm_out, (unsigned short*)xb);  // hb aliases xb

    // layer 2
    agg_kernel<<<(N_NODES + 3) / 4, 256, 0, stream>>>(xb, norm_in, row_off, csr_src, aggb);
    gemm2_mfma_kernel<<<(N_NODES + 63) / 64, 256, 0, stream>>>(
        (const unsigned short*)aggb, W2, b2, out);
}